// Round 1
// baseline (164.470 us; speedup 1.0000x reference)
//
#include <hip/hip_runtime.h>

// CompactPiecewiseLinearEmbeddings: out[n,f,:] = C[f][k] + t*(C[f][k+1]-C[f][k])
// where k = #{j in [1,47] : edges[f][j] <= x[n,f]}, t = (x - edges[f][k]) / width[f][k],
// C[f][j] = bias[f] + sum_{b<j} W[f][b][:]   (exploits sorted boundaries: h = [1..1, t, 0..0])

#define NN 16384
#define FF 256
#define BB 48
#define DD 8

#define FT 16              // features per block
#define NSPLIT 128         // n-splits
#define NPB (NN / NSPLIT)  // 128 rows per block

#define ESTR 17            // [j][ESTR] transposed edge table stride (coprime to 32 banks)
#define CSTR (49 * DD + 4) // 396 floats per feature (pad +4 breaks 8f mod-32 bank pattern)

__global__ __launch_bounds__(256, 5)
void cple_kernel(const float* __restrict__ X,
                 const float* __restrict__ Edg,
                 const float* __restrict__ Wid,
                 const float* __restrict__ W,
                 const float* __restrict__ Bias,
                 float* __restrict__ Out)
{
    __shared__ float sE[49 * ESTR];   // edges transposed, j=0..48 (48 = +inf sentinel)
    __shared__ float sR[48 * ESTR];   // 1/width transposed
    __shared__ float sC[FT * CSTR];   // cumulative W + bias, [f][j=0..48][d]

    const int tid = threadIdx.x;
    const int f0  = blockIdx.x * FT;
    const int ns  = blockIdx.y;

    // --- stage W tile into sC at [f][b+1][d] (contiguous 6144-float chunk, float4) ---
    {
        const float4* Wt4 = (const float4*)(W + (size_t)f0 * BB * DD);
        for (int idx4 = tid; idx4 < FT * BB * DD / 4; idx4 += 256) {
            float4 v = Wt4[idx4];
            int idx = idx4 * 4;
            int f   = idx / (BB * DD);
            int rem = idx - f * (BB * DD);
            int b   = rem >> 3;
            int d   = rem & 7;
            float* dst = &sC[f * CSTR + (b + 1) * DD + d];
            dst[0] = v.x; dst[1] = v.y; dst[2] = v.z; dst[3] = v.w;
        }
    }
    // --- stage edges & reciprocal widths (transposed) ---
    for (int idx = tid; idx < FT * BB; idx += 256) {
        int f = idx / BB;
        int j = idx - f * BB;
        sE[j * ESTR + f] = Edg[(size_t)(f0 + f) * BB + j];
        sR[j * ESTR + f] = 1.0f / Wid[(size_t)(f0 + f) * BB + j];
    }
    if (tid < FT) sE[48 * ESTR + tid] = __builtin_inff();  // sentinel for search probe j=48
    __syncthreads();

    // --- in-place inclusive scan: C[f][j][d] = bias + sum_{b<j} W[f][b][d] ---
    if (tid < FT * DD) {
        int f = tid >> 3;
        int d = tid & 7;
        float acc = Bias[(size_t)(f0 + f) * DD + d];
        float* c = &sC[f * CSTR + d];
        c[0] = acc;
        #pragma unroll
        for (int b = 1; b <= BB; ++b) {
            acc += c[b * DD];   // holds W[f][b-1][d]
            c[b * DD] = acc;
        }
    }
    __syncthreads();

    // --- main loop: 16 lanes x 16 rows, 2 rows/thread/iter for ILP ---
    const int f_l  = tid & 15;
    const int n_l  = tid >> 4;
    const float* cF = &sC[f_l * CSTR];
    const int fcol = f0 + f_l;
    const float* xp = X + fcol;
    float* op = Out + (size_t)fcol * DD;

    const int n0 = ns * NPB + n_l;
    #pragma unroll
    for (int i = 0; i < NPB / 32; ++i) {
        int na = n0 + i * 32;
        int nb = na + 16;
        float xa = xp[(size_t)na * FF];
        float xb = xp[(size_t)nb * FF];

        // branchless binary search: k = count of edges[1..47] <= x
        int ka = 0, kb = 0;
        #pragma unroll
        for (int w = 32; w >= 1; w >>= 1) {
            ka += (xa >= sE[(ka + w) * ESTR + f_l]) ? w : 0;
            kb += (xb >= sE[(kb + w) * ESTR + f_l]) ? w : 0;
        }
        float ta = (xa - sE[ka * ESTR + f_l]) * sR[ka * ESTR + f_l];
        float tb = (xb - sE[kb * ESTR + f_l]) * sR[kb * ESTR + f_l];

        const float4* c4a = (const float4*)(cF + ka * DD);
        const float4* c4b = (const float4*)(cF + kb * DD);
        float4 a0 = c4a[0], a1 = c4a[1], a2 = c4a[2], a3 = c4a[3];
        float4 b0 = c4b[0], b1 = c4b[1], b2 = c4b[2], b3 = c4b[3];

        float4 oA0, oA1, oB0, oB1;
        oA0.x = fmaf(ta, a2.x - a0.x, a0.x);
        oA0.y = fmaf(ta, a2.y - a0.y, a0.y);
        oA0.z = fmaf(ta, a2.z - a0.z, a0.z);
        oA0.w = fmaf(ta, a2.w - a0.w, a0.w);
        oA1.x = fmaf(ta, a3.x - a1.x, a1.x);
        oA1.y = fmaf(ta, a3.y - a1.y, a1.y);
        oA1.z = fmaf(ta, a3.z - a1.z, a1.z);
        oA1.w = fmaf(ta, a3.w - a1.w, a1.w);
        oB0.x = fmaf(tb, b2.x - b0.x, b0.x);
        oB0.y = fmaf(tb, b2.y - b0.y, b0.y);
        oB0.z = fmaf(tb, b2.z - b0.z, b0.z);
        oB0.w = fmaf(tb, b2.w - b0.w, b0.w);
        oB1.x = fmaf(tb, b3.x - b1.x, b1.x);
        oB1.y = fmaf(tb, b3.y - b1.y, b1.y);
        oB1.z = fmaf(tb, b3.z - b1.z, b1.z);
        oB1.w = fmaf(tb, b3.w - b1.w, b1.w);

        float4* oa = (float4*)(op + (size_t)na * (FF * DD));
        float4* ob = (float4*)(op + (size_t)nb * (FF * DD));
        oa[0] = oA0; oa[1] = oA1;
        ob[0] = oB0; ob[1] = oB1;
    }
}

extern "C" void kernel_launch(void* const* d_in, const int* in_sizes, int n_in,
                              void* d_out, int out_size, void* d_ws, size_t ws_size,
                              hipStream_t stream) {
    const float* x     = (const float*)d_in[0];
    const float* edges = (const float*)d_in[1];
    const float* width = (const float*)d_in[2];
    const float* W     = (const float*)d_in[3];
    const float* b     = (const float*)d_in[4];
    float* out = (float*)d_out;

    dim3 grid(FF / FT, NSPLIT);
    cple_kernel<<<grid, 256, 0, stream>>>(x, edges, width, W, b, out);
}